// Round 1
// baseline (9729.633 us; speedup 1.0000x reference)
//
#include <hip/hip_runtime.h>
#include <math.h>

#define D_OPT   128
#define N_SIM   2048
#define M_STEPS 64
#define HID     64

// One thread per (path, option) element. Thread keeps S,V in registers across
// all 64 SDE steps. Weights are read with thread-uniform addresses so the
// compiler can scalarize them (s_load -> v_fmac v, s, v). Inner 64x64 GEMV is
// tiled: h1[64] fully unrolled (const-indexed regs), h2 in 16-wide tiles so
// both arrays stay in registers without exploding code size.
__global__ __launch_bounds__(256) void nsde_kernel(
    const float* __restrict__ S0p, const float* __restrict__ Kp,
    const float* __restrict__ Tp,  const float* __restrict__ rfp,
    const float* __restrict__ V0p, const float* __restrict__ rhop,
    const float* __restrict__ Z1,  const float* __restrict__ Z2r,
    const float* __restrict__ W1,  const float* __restrict__ B1,
    const float* __restrict__ W2,  const float* __restrict__ B2,
    const float* __restrict__ W3,  const float* __restrict__ B3,
    float* __restrict__ out)
{
    const int e = blockIdx.x * 256 + threadIdx.x;     // [0, 262144)
    const int d = e & (D_OPT - 1);

    const float rf    = rfp[0];
    const float rho   = rhop[0];
    const float rho_c = sqrtf(1.0f - rho * rho);
    const float Td    = Tp[d];
    const float dt    = Td * (1.0f / (float)M_STEPS);
    const float sdt   = sqrtf(dt);

    float S = S0p[d];
    float V = V0p[0];

    #pragma unroll 1
    for (int s = 0; s < M_STEPS; ++s) {
        const size_t zoff = (size_t)s * (size_t)(N_SIM * D_OPT) + (size_t)e;
        const float z1  = Z1[zoff];
        const float z2r = Z2r[zoff];
        const float z2  = rho * z1 + rho_c * z2r;
        const float tj  = dt * (float)s;

        float N[4];
        #pragma unroll 1
        for (int k = 0; k < 4; ++k) {
            const float* __restrict__ w1  = W1 + k * 4 * HID;
            const float* __restrict__ bb1 = B1 + k * HID;
            const float* __restrict__ w2  = W2 + k * HID * HID;
            const float* __restrict__ bb2 = B2 + k * HID;
            const float* __restrict__ w3  = W3 + k * HID;

            // Layer 1: feat [S, V, rf, dt*j] @ W1[4,64] + b1, ReLU
            float h1[HID];
            #pragma unroll
            for (int j = 0; j < HID; ++j) {
                float a = bb1[j];
                a = fmaf(S,  w1[0 * HID + j], a);
                a = fmaf(V,  w1[1 * HID + j], a);
                a = fmaf(rf, w1[2 * HID + j], a);
                a = fmaf(tj, w1[3 * HID + j], a);
                h1[j] = fmaxf(a, 0.0f);
            }

            // Layer 2 (64x64) tiled by 16 outputs + fused layer-3 dot
            float o = B3[k];
            #pragma unroll 1
            for (int jt = 0; jt < 4; ++jt) {
                float h2[16];
                #pragma unroll
                for (int jj = 0; jj < 16; ++jj) h2[jj] = bb2[jt * 16 + jj];
                #pragma unroll
                for (int i = 0; i < HID; ++i) {
                    const float hv = h1[i];
                    #pragma unroll
                    for (int jj = 0; jj < 16; ++jj)
                        h2[jj] = fmaf(hv, w2[i * HID + jt * 16 + jj], h2[jj]);
                }
                #pragma unroll
                for (int jj = 0; jj < 16; ++jj)
                    o = fmaf(fmaxf(h2[jj], 0.0f), w3[jt * 16 + jj], o);
            }

            // tanh(o) = 1 - 2/(e^{2o}+1); saturates correctly for |o| large
            const float ex = __expf(2.0f * o);
            N[k] = 1.0f - 2.0f / (ex + 1.0f);
        }

        S = S * (1.0f + N[0] * dt + N[1] * sdt * z1);
        V = V * (1.0f + N[2] * dt + N[3] * sdt * z2);
    }

    const float payoff  = fmaxf(S - Kp[d], 0.0f);
    const float contrib = __expf(-rf * Td) * payoff * (1.0f / (float)N_SIM);
    atomicAdd(&out[d], contrib);
}

extern "C" void kernel_launch(void* const* d_in, const int* in_sizes, int n_in,
                              void* d_out, int out_size, void* d_ws, size_t ws_size,
                              hipStream_t stream)
{
    const float* S0  = (const float*)d_in[0];
    const float* K   = (const float*)d_in[1];
    const float* T   = (const float*)d_in[2];
    const float* rf  = (const float*)d_in[3];
    const float* V0  = (const float*)d_in[4];
    const float* rho = (const float*)d_in[5];
    const float* Z1  = (const float*)d_in[6];
    const float* Z2r = (const float*)d_in[7];
    const float* W1  = (const float*)d_in[8];
    const float* B1  = (const float*)d_in[9];
    const float* W2  = (const float*)d_in[10];
    const float* B2  = (const float*)d_in[11];
    const float* W3  = (const float*)d_in[12];
    const float* B3  = (const float*)d_in[13];
    float* out = (float*)d_out;

    // d_out is poisoned 0xAA before every call; we accumulate with atomics.
    hipMemsetAsync(out, 0, (size_t)out_size * sizeof(float), stream);

    const int total  = N_SIM * D_OPT;          // 262144
    const int block  = 256;
    const int grid   = total / block;          // 1024
    nsde_kernel<<<grid, block, 0, stream>>>(S0, K, T, rf, V0, rho, Z1, Z2r,
                                            W1, B1, W2, B2, W3, B3, out);
}